// Round 1
// baseline (304.349 us; speedup 1.0000x reference)
//
#include <hip/hip_runtime.h>
#include <math.h>

#define TN 4096
#define HN 2048
#define NB 32
#define NCH 9
#define NCODES 512
#define CDIM 64

__device__ __forceinline__ float2 cmulf(float2 a, float2 b) {
    return make_float2(a.x * b.x - a.y * b.y, a.x * b.y + a.y * b.x);
}

__global__ __launch_bounds__(256) void zero_kernel(float* __restrict__ p, int n) {
    int i = blockIdx.x * 256 + threadIdx.x;
    if (i < n) p[i] = 0.0f;
}

// One block per (b, c) row. Radix-2 Stockham FFT (LDS ping-pong), Hilbert
// multiplier h[k]/N, inverse FFT, atan2 -> atomic mean over channels.
__global__ __launch_bounds__(256) void hilbert_phase_kernel(
    const float* __restrict__ x, float* __restrict__ phases) {
    __shared__ float2 bufA[TN];     // 32 KB
    __shared__ float2 bufB[TN];     // 32 KB
    __shared__ float2 tw[HN];       // 16 KB: tw[i] = exp(-i*pi*i/2048)
    const int tid = threadIdx.x;
    const int row = blockIdx.x;         // b*9 + c
    const int b = row / NCH;
    const float* xr = x + (size_t)row * TN;

    for (int i = tid; i < HN; i += 256) {
        float ang = -3.14159265358979323846f * ((float)i / (float)HN);
        float s, c;
        sincosf(ang, &s, &c);
        tw[i] = make_float2(c, s);
    }
    for (int i = tid; i < TN; i += 256) {
        bufA[i] = make_float2(xr[i], 0.0f);
    }
    __syncthreads();

    float2* src = bufA;
    float2* dst = bufB;
    // ---- forward FFT (12 stages) ----
    for (int stage = 0; stage < 12; ++stage) {
        const int m = 1 << stage;
        for (int idx = tid; idx < HN; idx += 256) {
            const int kk = idx & (m - 1);
            const int jm = idx - kk;               // j*m
            float2 a = src[idx];
            float2 bb = src[idx + HN];
            float2 w = tw[jm];
            float2 sum = make_float2(a.x + bb.x, a.y + bb.y);
            float2 dif = make_float2(a.x - bb.x, a.y - bb.y);
            dst[2 * jm + kk] = sum;
            dst[2 * jm + kk + m] = cmulf(dif, w);
        }
        __syncthreads();
        float2* t0 = src; src = dst; dst = t0;
    }
    // src now holds X[k] in natural order. Apply h[k]/N.
    const float inv = 1.0f / (float)TN;
    for (int i = tid; i < TN; i += 256) {
        float sc;
        if (i == 0 || i == HN) sc = inv;
        else if (i < HN) sc = 2.0f * inv;
        else sc = 0.0f;
        float2 v = src[i];
        v.x *= sc; v.y *= sc;
        src[i] = v;
    }
    __syncthreads();
    // ---- inverse FFT (conjugate twiddles, scale already folded in) ----
    for (int stage = 0; stage < 12; ++stage) {
        const int m = 1 << stage;
        for (int idx = tid; idx < HN; idx += 256) {
            const int kk = idx & (m - 1);
            const int jm = idx - kk;
            float2 a = src[idx];
            float2 bb = src[idx + HN];
            float2 w = tw[jm];
            w.y = -w.y;
            float2 sum = make_float2(a.x + bb.x, a.y + bb.y);
            float2 dif = make_float2(a.x - bb.x, a.y - bb.y);
            dst[2 * jm + kk] = sum;
            dst[2 * jm + kk + m] = cmulf(dif, w);
        }
        __syncthreads();
        float2* t0 = src; src = dst; dst = t0;
    }
    // src holds the analytic signal. phase = atan2(im, re); mean over 9 ch.
    float* ph = phases + (size_t)b * TN;
    for (int i = tid; i < TN; i += 256) {
        float2 v = src[i];
        float p = atan2f(v.y, v.x);
        atomicAdd(&ph[i], p * (1.0f / 9.0f));
    }
}

// 256 blocks x 256 threads, 512 points/block (2 per thread).
// Codebook + norms staged in LDS; features in registers; argmin via
// score = ||c||^2 - 2 f.c (fn is per-point constant); first-min tie-break.
__global__ __launch_bounds__(256, 1) void vq_kernel(
    const float* __restrict__ imu,
    const float* __restrict__ Wm, const float* __restrict__ bm,
    const float* __restrict__ Wp, const float* __restrict__ bp,
    const float* __restrict__ cb,
    const float* __restrict__ phases,
    float* __restrict__ out_q, float* __restrict__ out_i) {
    __shared__ __align__(16) float s_cb[NCODES * CDIM];   // 128 KB
    __shared__ float s_cn[NCODES];
    __shared__ float s_wm[32 * 9];
    __shared__ float s_wp[32 * 9];
    __shared__ float s_bm[32];
    __shared__ float s_bp[32];
    __shared__ int s_idx[512];
    const int tid = threadIdx.x;

    for (int i = tid; i < NCODES * CDIM / 4; i += 256)
        ((float4*)s_cb)[i] = ((const float4*)cb)[i];
    for (int i = tid; i < 288; i += 256) {
        if (i < 288) { s_wm[i] = Wm[i]; s_wp[i] = Wp[i]; }
    }
    if (tid < 32) { s_bm[tid] = bm[tid]; s_bp[tid] = bp[tid]; }
    __syncthreads();
    for (int k = tid; k < NCODES; k += 256) {
        float s = 0.0f;
        #pragma unroll
        for (int d = 0; d < CDIM; ++d) {
            float v = s_cb[k * CDIM + d];
            s = fmaf(v, v, s);
        }
        s_cn[k] = s;
    }
    __syncthreads();

    const int p0 = blockIdx.x * 512;

    float f0[CDIM], f1[CDIM];
    #pragma unroll
    for (int pp = 0; pp < 2; ++pp) {
        const int p = p0 + pp * 256 + tid;
        float* f = pp ? f1 : f0;
        const int b = p >> 12;
        const int t = p & (TN - 1);
        float xc[9];
        #pragma unroll
        for (int c = 0; c < 9; ++c)
            xc[c] = imu[((size_t)(b * 9 + c)) * TN + t];
        float phv = phases[p];
        float sp, cp;
        sincosf(phv, &sp, &cp);
        #pragma unroll
        for (int j = 0; j < 32; ++j) {
            float a = s_bm[j];
            #pragma unroll
            for (int c = 0; c < 9; ++c) a = fmaf(s_wm[j * 9 + c], xc[c], a);
            f[j] = a;
        }
        #pragma unroll
        for (int j = 0; j < 32; ++j) {
            float a = s_bp[j];
            #pragma unroll
            for (int c = 0; c < 7; ++c) a = fmaf(s_wp[j * 9 + c], xc[c], a);
            a = fmaf(s_wp[j * 9 + 7], cp, a);
            a = fmaf(s_wp[j * 9 + 8], sp, a);
            f[32 + j] = a;
        }
    }

    float best0 = 3.4e38f, best1 = 3.4e38f;
    int bi0 = 0, bi1 = 0;
    for (int k = 0; k < NCODES; ++k) {
        const float4* c4 = (const float4*)(s_cb + k * CDIM);
        float acc0 = 0.0f, acc1 = 0.0f;
        #pragma unroll
        for (int q = 0; q < 16; ++q) {
            float4 c = c4[q];
            acc0 = fmaf(f0[4 * q + 0], c.x, acc0);
            acc0 = fmaf(f0[4 * q + 1], c.y, acc0);
            acc0 = fmaf(f0[4 * q + 2], c.z, acc0);
            acc0 = fmaf(f0[4 * q + 3], c.w, acc0);
            acc1 = fmaf(f1[4 * q + 0], c.x, acc1);
            acc1 = fmaf(f1[4 * q + 1], c.y, acc1);
            acc1 = fmaf(f1[4 * q + 2], c.z, acc1);
            acc1 = fmaf(f1[4 * q + 3], c.w, acc1);
        }
        const float cn = s_cn[k];
        const float s0 = fmaf(-2.0f, acc0, cn);
        const float s1 = fmaf(-2.0f, acc1, cn);
        if (s0 < best0) { best0 = s0; bi0 = k; }
        if (s1 < best1) { best1 = s1; bi1 = k; }
    }

    s_idx[tid] = bi0;
    s_idx[256 + tid] = bi1;
    out_i[p0 + tid] = (float)bi0;
    out_i[p0 + 256 + tid] = (float)bi1;
    __syncthreads();

    float4* oq = (float4*)out_q;
    const float4* c4b = (const float4*)s_cb;
    for (int i = tid; i < 512 * 16; i += 256) {
        const int pt = i >> 4;
        const int q = i & 15;
        oq[(size_t)(p0 + pt) * 16 + q] = c4b[s_idx[pt] * 16 + q];
    }
}

extern "C" void kernel_launch(void* const* d_in, const int* in_sizes, int n_in,
                              void* d_out, int out_size, void* d_ws, size_t ws_size,
                              hipStream_t stream) {
    const float* imu = (const float*)d_in[0];
    const float* Wm  = (const float*)d_in[1];
    const float* bm  = (const float*)d_in[2];
    const float* Wp  = (const float*)d_in[3];
    const float* bp  = (const float*)d_in[4];
    const float* cb  = (const float*)d_in[5];

    float* out_q = (float*)d_out;                          // (32,4096,64)
    float* out_i = out_q + (size_t)NB * TN * CDIM;         // (32,4096) as float
    float* out_p = out_i + (size_t)NB * TN;                // (32,4096) phases

    zero_kernel<<<(NB * TN + 255) / 256, 256, 0, stream>>>(out_p, NB * TN);
    hilbert_phase_kernel<<<NB * NCH, 256, 0, stream>>>(imu, out_p);
    vq_kernel<<<(NB * TN) / 512, 256, 0, stream>>>(imu, Wm, bm, Wp, bp, cb,
                                                   out_p, out_q, out_i);
}